// Round 3
// baseline (12489.395 us; speedup 1.0000x reference)
//
#include <hip/hip_runtime.h>

#define NN 2048
#define NE 32768
#define DF 2048
#define TOPK 20
#define RMAXF 1e-5f
#define MAXD 48           // supported max in-degree (Poisson(16); verified by round-1 pass)
#define MAXDQ (MAXD / 4)  // 12 quad-levels of 4 packed edges
#define SENTW 0x08000800u // two packed sentinel ids (2048 -> PV[2048] == 0)
#define NSRC 4            // sources per block (float4-packed PV)
#define MAXROUNDS 64      // safety cap; provably unreachable (mass halves/round, conv <= ~20)

typedef __attribute__((ext_vector_type(4))) float f32x4;

// ---------------- init: zero counters, sentinel-fill transposed in-edge table ----------------
__global__ __launch_bounds__(256) void init_kernel(int* __restrict__ outcnt, int* __restrict__ incur,
                                                   unsigned* __restrict__ T) {
    int i = blockIdx.x * 256 + threadIdx.x;
    if (i < MAXDQ * NN * 2) T[i] = SENTW;
    if (i < NN) { outcnt[i] = 0; incur[i] = 0; }
}

// ---------------- build: out-degree counts + transposed (CSC) quad-packed fill ----------------
// Level-major: quad-level q of node j at uint2 index q*NN + j. Slot p of node d:
// word = (p>>2)*(NN*2) + d*2 + ((p>>1)&1), halfword = p&1. And+Or race only with the
// other half of the same word (disjoint masks) -> safe.
__global__ __launch_bounds__(256) void build_kernel(const int* __restrict__ ei, int* __restrict__ outcnt,
                                                    int* __restrict__ incur, unsigned* __restrict__ T) {
    int e = blockIdx.x * 256 + threadIdx.x;
    if (e >= NE) return;
    int s = ei[e];
    int d = ei[NE + e];
    atomicAdd(&outcnt[s], 1);
    int p = atomicAdd(&incur[d], 1);
    if (p < MAXD) {
        int wi = (p >> 2) * (NN * 2) + d * 2 + ((p >> 1) & 1);
        int sh = (p & 1) * 16;
        atomicAnd(&T[wi], ~(0xFFFFu << sh));
        atomicOr(&T[wi], ((unsigned)s) << sh);
    }
}

// ---------------- winv05 = 0.5/outdeg; per-64-node-group quad-level bound ----------------
__global__ __launch_bounds__(256) void meta_kernel(const int* __restrict__ outcnt, const int* __restrict__ incur,
                                                   float* __restrict__ winv05, int* __restrict__ gmaxq) {
    int tid = threadIdx.x;
#pragma unroll
    for (int l = 0; l < 8; ++l) {
        int j = tid + (l << 8);
        int c = outcnt[j];
        winv05[j] = c ? 0.5f / (float)c : 0.0f;  // deg==0 row spreads nothing
    }
    if (tid < 32) {
        int m = 0;
        for (int k = 0; k < 64; ++k) m = max(m, incur[tid * 64 + k]);
        m = min(m, MAXD);
        gmaxq[tid] = (m + 3) >> 2;
    }
}

// ---------------- 4-source local push (gather form) + per-wave top-20 ----------------
// PV is float4-packed: component c is source (4*blockIdx + c). One ds_read_b128 per
// edge-id services all 4 sources (4x fewer LDS instrs -> attacks the measured LDS-pipe
// saturation: 1.27e8 conflict cycles + ~100% LDS issue occupancy at round 1).
// Strided ownership: thread t owns nodes {t + 256*l} -> coalesced edge loads and a
// wave-uniform in-degree bound (j>>6 is constant across each wave for fixed l).
__global__ __launch_bounds__(256, 2) void push_topk_kernel(const unsigned* __restrict__ Tw,
                                                           const float* __restrict__ winv05g,
                                                           const int* __restrict__ gmaxqg,
                                                           float* __restrict__ tkv, int* __restrict__ tki) {
    __shared__ f32x4 PV[NN + 1];  // PV[2048] = always-zero sentinel
    __shared__ int sflag;

    const int tid = threadIdx.x;
    const int s0 = blockIdx.x * NSRC;
    const uint2* Tq = (const uint2*)Tw;
    const f32x4 z = {0.f, 0.f, 0.f, 0.f};

    f32x4 Rr[8], Pr[8], dreg[8];
    float wv[8];
    int gmq[8];
#pragma unroll
    for (int l = 0; l < 8; ++l) {
        int j = tid + (l << 8);
        Rr[l] = z;
        Pr[l] = z;
        wv[l] = winv05g[j];
        gmq[l] = gmaxqg[j >> 6];
        PV[j] = z;
    }
    if (tid == 0) { PV[NN] = z; sflag = 0; }
    // fold reference round 1 (only the source is >= RMAX): P[s][c]=0.5, PV[s][c]=winv05[s]
#pragma unroll
    for (int l = 0; l < 8; ++l) {
        int j = tid + (l << 8);
#pragma unroll
        for (int c = 0; c < NSRC; ++c) {
            if (j == s0 + c) {
                Pr[l][c] = 0.5f;
                ((float*)&PV[j])[c] = wv[l];  // compile-time c -> single ds_write_b32
            }
        }
    }
    __syncthreads();

    int flagreg = 1;
    for (int round = 0; flagreg && round < MAXROUNDS; ++round) {
        // gather: d[j] += PV[i] over in-edges i->j (sentinel slots add PV[2048]=0)
#pragma unroll
        for (int l = 0; l < 8; ++l) {
            int j = tid + (l << 8);
            const uint2* colq = Tq + j;
            int gq = __builtin_amdgcn_readfirstlane(gmq[l]);  // wave-uniform bound
            f32x4 d = z;
#pragma unroll 2
            for (int q = 0; q < gq; ++q) {
                uint2 w = colq[q * NN];  // coalesced 512B/wave, L2/L3-resident
                d += PV[w.x & 0xFFFFu];
                d += PV[w.x >> 16];
                d += PV[w.y & 0xFFFFu];
                d += PV[w.y >> 16];
            }
            dreg[l] = d;
        }
        __syncthreads();  // all PV reads done before PV rewrite
        if (tid == 0) sflag = 0;
        __syncthreads();
        bool above = false;
#pragma unroll
        for (int l = 0; l < 8; ++l) {
            int j = tid + (l << 8);
            f32x4 rn = Rr[l] + dreg[l];
            f32x4 pv;
#pragma unroll
            for (int u = 0; u < 4; ++u) {
                float r = rn[u];
                if (r >= RMAXF) {
                    Pr[l][u] += 0.5f * r;
                    pv[u] = r * wv[l];
                    rn[u] = 0.0f;
                    above = true;
                } else {
                    pv[u] = 0.0f;
                }
            }
            PV[j] = pv;
            Rr[l] = rn;
        }
        if (above) sflag = 1;  // racy 1-stores, benign
        __syncthreads();
        flagreg = sflag;
    }

    // ---- top-20: dump P into dead PV, then wave w extracts source s0+w (barrier-free) ----
#pragma unroll
    for (int l = 0; l < 8; ++l) PV[tid + (l << 8)] = Pr[l];
    __syncthreads();

    const int w = tid >> 6;   // wave id == source component; waves touch disjoint components
    const int lane = tid & 63;
    float* Psh = (float*)PV;  // value of node n, source w at Psh[(n<<2) + w]

    float bv = -2.0f;
    int bi = 0;
#pragma unroll
    for (int k = 0; k < 32; ++k) {  // k ascending => node ascending; strict > keeps lowest
        int n = lane + (k << 6);
        float v = Psh[(n << 2) + w];
        if (v > bv) { bv = v; bi = n; }
    }
    for (int s = 0; s < TOPK; ++s) {
        float mv = bv;
        int mi = bi;
#pragma unroll
        for (int off = 32; off > 0; off >>= 1) {  // butterfly argmax, lowest index on ties
            float ov = __shfl_xor(mv, off, 64);
            int oi = __shfl_xor(mi, off, 64);
            if (ov > mv || (ov == mv && oi < mi)) { mv = ov; mi = oi; }
        }
        if (lane == 0) {
            tkv[(s0 + w) * TOPK + s] = mv;
            tki[(s0 + w) * TOPK + s] = mi;
        }
        if ((mi & 63) == lane) {  // owner pops winner, rescans its 32 (static indexing only)
            Psh[(mi << 2) + w] = -1.0f;  // P >= 0, safe sentinel
            bv = -2.0f;
            bi = 0;
#pragma unroll
            for (int k = 0; k < 32; ++k) {
                int n = lane + (k << 6);
                float v = Psh[(n << 2) + w];
                if (v > bv) { bv = v; bi = n; }
            }
        }
    }
}

// ---------------- out[row] = sum_v w_v * feats[idx_v] ----------------
__global__ __launch_bounds__(256) void final_kernel(const float* __restrict__ feats, const float* __restrict__ tkv,
                                                    const int* __restrict__ tki, float* __restrict__ out) {
    __shared__ float wvs[TOPK];
    __shared__ int wis[TOPK];
    int row = blockIdx.x, tid = threadIdx.x;
    if (tid < TOPK) {
        wvs[tid] = tkv[row * TOPK + tid];
        wis[tid] = tki[row * TOPK + tid];
    }
    __syncthreads();
    int c0 = tid * 8;
    float4 a0 = {0, 0, 0, 0}, a1 = {0, 0, 0, 0};
    for (int v = 0; v < TOPK; ++v) {
        float w = wvs[v];
        int id = wis[v];
        const float4* fr = (const float4*)&feats[(size_t)id * DF + c0];
        float4 g0 = fr[0], g1 = fr[1];
        a0.x += w * g0.x; a0.y += w * g0.y; a0.z += w * g0.z; a0.w += w * g0.w;
        a1.x += w * g1.x; a1.y += w * g1.y; a1.z += w * g1.z; a1.w += w * g1.w;
    }
    float4* op = (float4*)&out[(size_t)row * DF + c0];
    op[0] = a0;
    op[1] = a1;
}

extern "C" void kernel_launch(void* const* d_in, const int* in_sizes, int n_in,
                              void* d_out, int out_size, void* d_ws, size_t ws_size,
                              hipStream_t stream) {
    const float* feats = (const float*)d_in[0];
    const int* ei = (const int*)d_in[1];
    float* out = (float*)d_out;

    int* outcnt = (int*)d_ws;                     // 2048
    int* incur = outcnt + NN;                     // 2048 (in-degree after build)
    float* winv05 = (float*)(incur + NN);         // 2048
    int* gmaxq = (int*)(winv05 + NN);             // 64 (32 used; keeps T 8B-aligned)
    unsigned* T = (unsigned*)(gmaxq + 64);        // 12*2048*2 words (quad-packed CSC)
    float* tkv = (float*)(T + MAXDQ * NN * 2);    // 2048*20
    int* tki = (int*)(tkv + NN * TOPK);           // 2048*20

    init_kernel<<<(MAXDQ * NN * 2 + 255) / 256, 256, 0, stream>>>(outcnt, incur, T);
    build_kernel<<<(NE + 255) / 256, 256, 0, stream>>>(ei, outcnt, incur, T);
    meta_kernel<<<1, 256, 0, stream>>>(outcnt, incur, winv05, gmaxq);
    push_topk_kernel<<<NN / NSRC, 256, 0, stream>>>(T, winv05, gmaxq, tkv, tki);
    final_kernel<<<NN, 256, 0, stream>>>(feats, tkv, tki, out);
}

// Round 4
// 7327.512 us; speedup vs baseline: 1.7045x; 1.7045x over previous
//
#include <hip/hip_runtime.h>

#define NN 2048
#define NE 32768
#define DF 2048
#define TOPK 20
#define RMAXF 1e-5f
#define MAXD 48           // supported max in-degree (Poisson(16); verified by passing rounds)
#define MAXDQ (MAXD / 4)  // 12 quad-levels of 4 packed edges
#define SENTW 0x08000800u // two packed sentinel ids (2048 -> PV[sentinel] == 0)
#define NSRC 4            // sources per block (float4-packed PV)
#define MAXROUNDS 64      // safety cap; provably unreachable (mass halves/round)

typedef __attribute__((ext_vector_type(4))) float f32x4;

// ---------------- init: zero counters, sentinel-fill transposed in-edge table ----------------
__global__ __launch_bounds__(256) void init_kernel(int* __restrict__ outcnt, int* __restrict__ incur,
                                                   unsigned* __restrict__ T) {
    int i = blockIdx.x * 256 + threadIdx.x;
    if (i < MAXDQ * NN * 2) T[i] = SENTW;
    if (i < NN) { outcnt[i] = 0; incur[i] = 0; }
}

// ---------------- build: out-degree counts + transposed (CSC) quad-packed fill ----------------
// Level-major: quad-level q of node j at uint2 index q*NN + j. Slot p of node d:
// word = (p>>2)*(NN*2) + d*2 + ((p>>1)&1), halfword = p&1. And+Or race only with the
// other half of the same word (disjoint masks) -> safe.
__global__ __launch_bounds__(256) void build_kernel(const int* __restrict__ ei, int* __restrict__ outcnt,
                                                    int* __restrict__ incur, unsigned* __restrict__ T) {
    int e = blockIdx.x * 256 + threadIdx.x;
    if (e >= NE) return;
    int s = ei[e];
    int d = ei[NE + e];
    atomicAdd(&outcnt[s], 1);
    int p = atomicAdd(&incur[d], 1);
    if (p < MAXD) {
        int wi = (p >> 2) * (NN * 2) + d * 2 + ((p >> 1) & 1);
        int sh = (p & 1) * 16;
        atomicAnd(&T[wi], ~(0xFFFFu << sh));
        atomicOr(&T[wi], ((unsigned)s) << sh);
    }
}

// ---------------- winv05 = 0.5/outdeg; per-64-node-group quad-level bound ----------------
__global__ __launch_bounds__(256) void meta_kernel(const int* __restrict__ outcnt, const int* __restrict__ incur,
                                                   float* __restrict__ winv05, int* __restrict__ gmaxq) {
    int tid = threadIdx.x;
#pragma unroll
    for (int l = 0; l < 8; ++l) {
        int j = tid + (l << 8);
        int c = outcnt[j];
        winv05[j] = c ? 0.5f / (float)c : 0.0f;  // deg==0 row spreads nothing
    }
    if (tid < 32) {
        int m = 0;
        for (int k = 0; k < 64; ++k) m = max(m, incur[tid * 64 + k]);
        m = min(m, MAXD);
        gmaxq[tid] = (m + 3) >> 2;
    }
}

// ---------------- 4-source local push (gather form, ping-pong PV) + per-wave top-20 ----------------
// PV float4-packed: component c = source 4*blockIdx+c. One ds_read_b128 per edge-id serves
// 4 sources. Ping-pong buffers fuse gather+update per l (no dreg[8] array -> no spill; the
// round-3 regression was scratch traffic: WRITE_SIZE 44.9 GB). One barrier per round.
// Convergence flag: per-wave slots written unconditionally each round, parity-alternated
// (reuse separated by the intervening round's barrier -> no reset, no race).
__global__ __launch_bounds__(256, 1) void push_topk_kernel(const unsigned* __restrict__ Tw,
                                                           const float* __restrict__ winv05g,
                                                           const int* __restrict__ gmaxqg,
                                                           float* __restrict__ tkv, int* __restrict__ tki) {
    __shared__ f32x4 PVbuf[2 * (NN + 1)];  // [parity][node]; PV*[NN] = always-zero sentinel
    __shared__ int swf[2][4];              // [parity][wave] convergence flags

    const int tid = threadIdx.x;
    const int lane = tid & 63;
    const int wvid = tid >> 6;
    const int s0 = blockIdx.x * NSRC;
    const uint2* Tq = (const uint2*)Tw;
    const f32x4 z = {0.f, 0.f, 0.f, 0.f};

    f32x4 Rr[8], Pr[8];
    float wvv[8];
    int gq0, gq1, gq2, gq3, gq4, gq5, gq6, gq7;  // wave-uniform in-degree bounds -> SGPRs
    gq0 = __builtin_amdgcn_readfirstlane(gmaxqg[wvid + 0]);
    gq1 = __builtin_amdgcn_readfirstlane(gmaxqg[wvid + 4]);
    gq2 = __builtin_amdgcn_readfirstlane(gmaxqg[wvid + 8]);
    gq3 = __builtin_amdgcn_readfirstlane(gmaxqg[wvid + 12]);
    gq4 = __builtin_amdgcn_readfirstlane(gmaxqg[wvid + 16]);
    gq5 = __builtin_amdgcn_readfirstlane(gmaxqg[wvid + 20]);
    gq6 = __builtin_amdgcn_readfirstlane(gmaxqg[wvid + 24]);
    gq7 = __builtin_amdgcn_readfirstlane(gmaxqg[wvid + 28]);

#pragma unroll
    for (int l = 0; l < 8; ++l) {
        int j = tid + (l << 8);
        Rr[l] = z;
        Pr[l] = z;
        wvv[l] = winv05g[j];
        PVbuf[j] = z;  // buffer 0; buffer 1 is fully written in round 0 before round 1 reads it
    }
    if (tid == 0) { PVbuf[NN] = z; PVbuf[2 * NN + 1] = z; }  // both sentinels, never rewritten
    // fold reference round 1 (only the source is >= RMAX): P[s][c]=0.5, PV0[s][c]=winv05[s]
#pragma unroll
    for (int l = 0; l < 8; ++l) {
        int j = tid + (l << 8);
#pragma unroll
        for (int c = 0; c < NSRC; ++c) {
            if (j == s0 + c) {
                Pr[l][c] = 0.5f;
                ((float*)&PVbuf[j])[c] = wvv[l];  // compile-time c -> single ds_write_b32
            }
        }
    }
    __syncthreads();

    int flagreg = 1;
    for (int round = 0; flagreg && round < MAXROUNDS; ++round) {
        const int p = round & 1;
        const f32x4* PVc = PVbuf + p * (NN + 1);        // read buffer
        f32x4* PVn = PVbuf + (p ^ 1) * (NN + 1);        // write buffer
        bool above = false;
#pragma unroll
        for (int l = 0; l < 8; ++l) {
            int j = tid + (l << 8);
            const uint2* colq = Tq + j;
            int gq = (l == 0) ? gq0 : (l == 1) ? gq1 : (l == 2) ? gq2 : (l == 3) ? gq3
                   : (l == 4) ? gq4 : (l == 5) ? gq5 : (l == 6) ? gq6 : gq7;
            f32x4 d = z;
#pragma unroll 2
            for (int q = 0; q < gq; ++q) {
                uint2 w = colq[q * NN];  // coalesced 512B/wave, L2-resident
                d += PVc[w.x & 0xFFFFu];
                d += PVc[w.x >> 16];
                d += PVc[w.y & 0xFFFFu];
                d += PVc[w.y >> 16];
            }
            f32x4 rn = Rr[l] + d;
            f32x4 pv;
#pragma unroll
            for (int u = 0; u < 4; ++u) {
                float r = rn[u];
                if (r >= RMAXF) {
                    Pr[l][u] += 0.5f * r;
                    pv[u] = r * wvv[l];
                    rn[u] = 0.0f;
                    above = true;
                } else {
                    pv[u] = 0.0f;
                }
            }
            PVn[j] = pv;
            Rr[l] = rn;
        }
        int anyv = __any(above) ? 1 : 0;     // all lanes participate
        if (lane == 0) swf[p][wvid] = anyv;  // unconditional write -> no reset needed
        __syncthreads();                     // PVn writes + flags visible; PVc reads done
        flagreg = swf[p][0] | swf[p][1] | swf[p][2] | swf[p][3];
    }

    // ---- top-20: dump P into dead PV (buffer 0), wave w extracts source s0+w ----
#pragma unroll
    for (int l = 0; l < 8; ++l) PVbuf[tid + (l << 8)] = Pr[l];
    __syncthreads();

    const int w = wvid;       // wave id == source component; waves touch disjoint components
    float* Psh = (float*)PVbuf;  // value of node n, source w at Psh[(n<<2) + w]

    float bv = -2.0f;
    int bi = 0;
#pragma unroll
    for (int k = 0; k < 32; ++k) {  // k ascending => node ascending; strict > keeps lowest
        int n = lane + (k << 6);
        float v = Psh[(n << 2) + w];
        if (v > bv) { bv = v; bi = n; }
    }
    for (int s = 0; s < TOPK; ++s) {
        float mv = bv;
        int mi = bi;
#pragma unroll
        for (int off = 32; off > 0; off >>= 1) {  // butterfly argmax, lowest index on ties
            float ov = __shfl_xor(mv, off, 64);
            int oi = __shfl_xor(mi, off, 64);
            if (ov > mv || (ov == mv && oi < mi)) { mv = ov; mi = oi; }
        }
        if (lane == 0) {
            tkv[(s0 + w) * TOPK + s] = mv;
            tki[(s0 + w) * TOPK + s] = mi;
        }
        if ((mi & 63) == lane) {  // owner pops winner, rescans its 32 (static indexing only)
            Psh[(mi << 2) + w] = -1.0f;  // P >= 0, safe sentinel
            bv = -2.0f;
            bi = 0;
#pragma unroll
            for (int k = 0; k < 32; ++k) {
                int n = lane + (k << 6);
                float v = Psh[(n << 2) + w];
                if (v > bv) { bv = v; bi = n; }
            }
        }
    }
}

// ---------------- out[row] = sum_v w_v * feats[idx_v] ----------------
__global__ __launch_bounds__(256) void final_kernel(const float* __restrict__ feats, const float* __restrict__ tkv,
                                                    const int* __restrict__ tki, float* __restrict__ out) {
    __shared__ float wvs[TOPK];
    __shared__ int wis[TOPK];
    int row = blockIdx.x, tid = threadIdx.x;
    if (tid < TOPK) {
        wvs[tid] = tkv[row * TOPK + tid];
        wis[tid] = tki[row * TOPK + tid];
    }
    __syncthreads();
    int c0 = tid * 8;
    float4 a0 = {0, 0, 0, 0}, a1 = {0, 0, 0, 0};
    for (int v = 0; v < TOPK; ++v) {
        float w = wvs[v];
        int id = wis[v];
        const float4* fr = (const float4*)&feats[(size_t)id * DF + c0];
        float4 g0 = fr[0], g1 = fr[1];
        a0.x += w * g0.x; a0.y += w * g0.y; a0.z += w * g0.z; a0.w += w * g0.w;
        a1.x += w * g1.x; a1.y += w * g1.y; a1.z += w * g1.z; a1.w += w * g1.w;
    }
    float4* op = (float4*)&out[(size_t)row * DF + c0];
    op[0] = a0;
    op[1] = a1;
}

extern "C" void kernel_launch(void* const* d_in, const int* in_sizes, int n_in,
                              void* d_out, int out_size, void* d_ws, size_t ws_size,
                              hipStream_t stream) {
    const float* feats = (const float*)d_in[0];
    const int* ei = (const int*)d_in[1];
    float* out = (float*)d_out;

    int* outcnt = (int*)d_ws;                     // 2048
    int* incur = outcnt + NN;                     // 2048 (in-degree after build)
    float* winv05 = (float*)(incur + NN);         // 2048
    int* gmaxq = (int*)(winv05 + NN);             // 64 (32 used; keeps T 8B-aligned)
    unsigned* T = (unsigned*)(gmaxq + 64);        // 12*2048*2 words (quad-packed CSC)
    float* tkv = (float*)(T + MAXDQ * NN * 2);    // 2048*20
    int* tki = (int*)(tkv + NN * TOPK);           // 2048*20

    init_kernel<<<(MAXDQ * NN * 2 + 255) / 256, 256, 0, stream>>>(outcnt, incur, T);
    build_kernel<<<(NE + 255) / 256, 256, 0, stream>>>(ei, outcnt, incur, T);
    meta_kernel<<<1, 256, 0, stream>>>(outcnt, incur, winv05, gmaxq);
    push_topk_kernel<<<NN / NSRC, 256, 0, stream>>>(T, winv05, gmaxq, tkv, tki);
    final_kernel<<<NN, 256, 0, stream>>>(feats, tkv, tki, out);
}

// Round 5
// 613.533 us; speedup vs baseline: 20.3565x; 11.9431x over previous
//
#include <hip/hip_runtime.h>

#define NN 2048
#define NE 32768
#define DF 2048
#define TOPK 20
#define RMAXF 1e-5f
#define MAXD 48           // supported max in-degree (Poisson(16); verified by passing rounds)
#define MAXDQ (MAXD / 4)  // 12 quad-levels of 4 packed edges
#define SENTW 0x08000800u // two packed sentinel ids (2048 -> PV[sentinel] == 0)
#define NSRC 4            // sources per block (float4-packed PV)
#define MAXROUNDS 64      // safety cap; provably unreachable (mass halves/round)

typedef __attribute__((ext_vector_type(4))) float f32x4;

// ---------------- init: zero counters, sentinel-fill transposed in-edge table ----------------
__global__ __launch_bounds__(256) void init_kernel(int* __restrict__ outcnt, int* __restrict__ incur,
                                                   unsigned* __restrict__ T) {
    int i = blockIdx.x * 256 + threadIdx.x;
    if (i < MAXDQ * NN * 2) T[i] = SENTW;
    if (i < NN) { outcnt[i] = 0; incur[i] = 0; }
}

// ---------------- build: out-degree counts + transposed (CSC) quad-packed fill ----------------
// Level-major: quad-level q of node j at uint2 index q*NN + j. Slot p of node d:
// word = (p>>2)*(NN*2) + d*2 + ((p>>1)&1), halfword = p&1. And+Or race only with the
// other half of the same word (disjoint masks) -> safe.
__global__ __launch_bounds__(256) void build_kernel(const int* __restrict__ ei, int* __restrict__ outcnt,
                                                    int* __restrict__ incur, unsigned* __restrict__ T) {
    int e = blockIdx.x * 256 + threadIdx.x;
    if (e >= NE) return;
    int s = ei[e];
    int d = ei[NE + e];
    atomicAdd(&outcnt[s], 1);
    int p = atomicAdd(&incur[d], 1);
    if (p < MAXD) {
        int wi = (p >> 2) * (NN * 2) + d * 2 + ((p >> 1) & 1);
        int sh = (p & 1) * 16;
        atomicAnd(&T[wi], ~(0xFFFFu << sh));
        atomicOr(&T[wi], ((unsigned)s) << sh);
    }
}

// ---------------- winv05 = 0.5/outdeg; per-64-node-group quad-level bound ----------------
__global__ __launch_bounds__(256) void meta_kernel(const int* __restrict__ outcnt, const int* __restrict__ incur,
                                                   float* __restrict__ winv05, int* __restrict__ gmaxq) {
    int tid = threadIdx.x;
#pragma unroll
    for (int l = 0; l < 8; ++l) {
        int j = tid + (l << 8);
        int c = outcnt[j];
        winv05[j] = c ? 0.5f / (float)c : 0.0f;  // deg==0 row spreads nothing
    }
    if (tid < 32) {
        int m = 0;
        for (int k = 0; k < 64; ++k) m = max(m, incur[tid * 64 + k]);
        m = min(m, MAXD);
        gmaxq[tid] = (m + 3) >> 2;
    }
}

// ---------------- 4-source local push (gather form, ping-pong PV) + per-wave top-20 ----------------
// 512 threads x 4 owned nodes: per-thread state = Rr[4]+Pr[4]+wvv[4] (~36 VGPRs) -- sized to
// round 1's proven-no-spill footprint. (Rounds 3/4 regressed on scratch: 8 owned nodes of
// f32x4 state blew past the VGPR budget -> 28-45 GB of HBM scratch traffic.)
// PV float4-packed: component c = source 4*blockIdx+c; one ds_read_b128 per edge-id serves
// 4 sources (4x fewer LDS instrs vs round 1's measured LDS-pipe saturation).
// Ping-pong buffers fuse gather+update (1 barrier/round). Convergence flag: per-wave slots
// written unconditionally each round, parity-alternated (no reset, no race).
__global__ __launch_bounds__(512, 2) void push_topk_kernel(const unsigned* __restrict__ Tw,
                                                           const float* __restrict__ winv05g,
                                                           const int* __restrict__ gmaxqg,
                                                           float* __restrict__ tkv, int* __restrict__ tki) {
    __shared__ f32x4 PVbuf[2 * (NN + 1)];  // [parity][node]; PV*[NN] = always-zero sentinel
    __shared__ int swf[2][8];              // [parity][wave] convergence flags

    const int tid = threadIdx.x;
    const int lane = tid & 63;
    const int wvid = tid >> 6;  // 0..7
    const int s0 = blockIdx.x * NSRC;
    const uint2* Tq = (const uint2*)Tw;
    const f32x4 z = {0.f, 0.f, 0.f, 0.f};

    f32x4 Rr[4], Pr[4];
    float wvv[4];
    // wave-uniform in-degree bounds -> SGPRs (node group of j = tid + l*512 is (tid>>6) + l*8)
    int gq0 = __builtin_amdgcn_readfirstlane(gmaxqg[wvid + 0]);
    int gq1 = __builtin_amdgcn_readfirstlane(gmaxqg[wvid + 8]);
    int gq2 = __builtin_amdgcn_readfirstlane(gmaxqg[wvid + 16]);
    int gq3 = __builtin_amdgcn_readfirstlane(gmaxqg[wvid + 24]);

#pragma unroll
    for (int l = 0; l < 4; ++l) {
        int j = tid + (l << 9);
        Rr[l] = z;
        Pr[l] = z;
        wvv[l] = winv05g[j];
        PVbuf[j] = z;  // buffer 0; buffer 1 is fully written in round 0 before round 1 reads it
    }
    if (tid == 0) { PVbuf[NN] = z; PVbuf[2 * NN + 1] = z; }  // both sentinels, never rewritten
    // fold reference round 1 (only the source is >= RMAX): P[s][c]=0.5, PV0[s][c]=winv05[s]
#pragma unroll
    for (int l = 0; l < 4; ++l) {
        int j = tid + (l << 9);
#pragma unroll
        for (int c = 0; c < NSRC; ++c) {
            if (j == s0 + c) {
                Pr[l][c] = 0.5f;
                ((float*)&PVbuf[j])[c] = wvv[l];  // compile-time c -> single ds_write_b32
            }
        }
    }
    __syncthreads();

    int flagreg = 1;
    for (int round = 0; flagreg && round < MAXROUNDS; ++round) {
        const int p = round & 1;
        const f32x4* PVc = PVbuf + p * (NN + 1);  // read buffer
        f32x4* PVn = PVbuf + (p ^ 1) * (NN + 1);  // write buffer
        bool above = false;
#pragma unroll
        for (int l = 0; l < 4; ++l) {
            int j = tid + (l << 9);
            const uint2* colq = Tq + j;
            int gq = (l == 0) ? gq0 : (l == 1) ? gq1 : (l == 2) ? gq2 : gq3;
            f32x4 d = z;
#pragma unroll 2
            for (int q = 0; q < gq; ++q) {
                uint2 w = colq[q * NN];  // coalesced 512B/wave, L2-resident
                d += PVc[w.x & 0xFFFFu];
                d += PVc[w.x >> 16];
                d += PVc[w.y & 0xFFFFu];
                d += PVc[w.y >> 16];
            }
            f32x4 rn = Rr[l] + d;
            f32x4 pv;
#pragma unroll
            for (int u = 0; u < 4; ++u) {
                float r = rn[u];
                if (r >= RMAXF) {
                    Pr[l][u] += 0.5f * r;
                    pv[u] = r * wvv[l];
                    rn[u] = 0.0f;
                    above = true;
                } else {
                    pv[u] = 0.0f;
                }
            }
            PVn[j] = pv;
            Rr[l] = rn;
        }
        int anyv = __any(above) ? 1 : 0;     // all lanes participate
        if (lane == 0) swf[p][wvid] = anyv;  // unconditional write -> no reset needed
        __syncthreads();                     // PVn writes + flags visible; PVc reads done
        flagreg = swf[p][0] | swf[p][1] | swf[p][2] | swf[p][3] |
                  swf[p][4] | swf[p][5] | swf[p][6] | swf[p][7];
    }

    // ---- top-20: dump P into dead PV (buffer 0); waves 0..3 each extract one source ----
#pragma unroll
    for (int l = 0; l < 4; ++l) PVbuf[tid + (l << 9)] = Pr[l];
    __syncthreads();

    const int w = wvid;  // wave id == source component
    if (w < NSRC) {
        float* Psh = (float*)PVbuf;  // value of node n, source w at Psh[(n<<2) + w]
        float bv = -2.0f;
        int bi = 0;
#pragma unroll
        for (int k = 0; k < 32; ++k) {  // k ascending => node ascending; strict > keeps lowest
            int n = lane + (k << 6);
            float v = Psh[(n << 2) + w];
            if (v > bv) { bv = v; bi = n; }
        }
        for (int s = 0; s < TOPK; ++s) {
            float mv = bv;
            int mi = bi;
#pragma unroll
            for (int off = 32; off > 0; off >>= 1) {  // butterfly argmax, lowest index on ties
                float ov = __shfl_xor(mv, off, 64);
                int oi = __shfl_xor(mi, off, 64);
                if (ov > mv || (ov == mv && oi < mi)) { mv = ov; mi = oi; }
            }
            if (lane == 0) {
                tkv[(s0 + w) * TOPK + s] = mv;
                tki[(s0 + w) * TOPK + s] = mi;
            }
            if ((mi & 63) == lane) {  // owner pops winner, rescans its 32 (static indexing only)
                Psh[(mi << 2) + w] = -1.0f;  // P >= 0, safe sentinel
                bv = -2.0f;
                bi = 0;
#pragma unroll
                for (int k = 0; k < 32; ++k) {
                    int n = lane + (k << 6);
                    float v = Psh[(n << 2) + w];
                    if (v > bv) { bv = v; bi = n; }
                }
            }
        }
    }
}

// ---------------- out[row] = sum_v w_v * feats[idx_v] ----------------
__global__ __launch_bounds__(256) void final_kernel(const float* __restrict__ feats, const float* __restrict__ tkv,
                                                    const int* __restrict__ tki, float* __restrict__ out) {
    __shared__ float wvs[TOPK];
    __shared__ int wis[TOPK];
    int row = blockIdx.x, tid = threadIdx.x;
    if (tid < TOPK) {
        wvs[tid] = tkv[row * TOPK + tid];
        wis[tid] = tki[row * TOPK + tid];
    }
    __syncthreads();
    int c0 = tid * 8;
    float4 a0 = {0, 0, 0, 0}, a1 = {0, 0, 0, 0};
    for (int v = 0; v < TOPK; ++v) {
        float w = wvs[v];
        int id = wis[v];
        const float4* fr = (const float4*)&feats[(size_t)id * DF + c0];
        float4 g0 = fr[0], g1 = fr[1];
        a0.x += w * g0.x; a0.y += w * g0.y; a0.z += w * g0.z; a0.w += w * g0.w;
        a1.x += w * g1.x; a1.y += w * g1.y; a1.z += w * g1.z; a1.w += w * g1.w;
    }
    float4* op = (float4*)&out[(size_t)row * DF + c0];
    op[0] = a0;
    op[1] = a1;
}

extern "C" void kernel_launch(void* const* d_in, const int* in_sizes, int n_in,
                              void* d_out, int out_size, void* d_ws, size_t ws_size,
                              hipStream_t stream) {
    const float* feats = (const float*)d_in[0];
    const int* ei = (const int*)d_in[1];
    float* out = (float*)d_out;

    int* outcnt = (int*)d_ws;                     // 2048
    int* incur = outcnt + NN;                     // 2048 (in-degree after build)
    float* winv05 = (float*)(incur + NN);         // 2048
    int* gmaxq = (int*)(winv05 + NN);             // 64 (32 used; keeps T 8B-aligned)
    unsigned* T = (unsigned*)(gmaxq + 64);        // 12*2048*2 words (quad-packed CSC)
    float* tkv = (float*)(T + MAXDQ * NN * 2);    // 2048*20
    int* tki = (int*)(tkv + NN * TOPK);           // 2048*20

    init_kernel<<<(MAXDQ * NN * 2 + 255) / 256, 256, 0, stream>>>(outcnt, incur, T);
    build_kernel<<<(NE + 255) / 256, 256, 0, stream>>>(ei, outcnt, incur, T);
    meta_kernel<<<1, 256, 0, stream>>>(outcnt, incur, winv05, gmaxq);
    push_topk_kernel<<<NN / NSRC, 512, 0, stream>>>(T, winv05, gmaxq, tkv, tki);
    final_kernel<<<NN, 256, 0, stream>>>(feats, tkv, tki, out);
}